// Round 2
// baseline (444.077 us; speedup 1.0000x reference)
//
#include <hip/hip_runtime.h>

#define F16 _Float16
typedef _Float16 f16x8 __attribute__((ext_vector_type(8)));
typedef _Float16 f16x4 __attribute__((ext_vector_type(4)));
typedef float f32x4 __attribute__((ext_vector_type(4)));

#define NB    4
#define CIN   512
#define NN    4096
#define KCH   256
#define OCH   512
#define BNEPS 1e-5f

// workspace layout (bytes)
#define XT_OFF   0u                    // [B][N][C]   f16  16 MB
#define KQT_OFF  (16u*1024*1024)       // [B][N][K]   f16   8 MB
#define VG_OFF   (24u*1024*1024)       // [B][V][N]   f16   8 MB
#define CTX_OFF  (32u*1024*1024)       // [B][N][V]   f16   8 MB

// ---------------------------------------------------------------- transpose
__global__ __launch_bounds__(256) void k_transpose(const float* __restrict__ x,
                                                   F16* __restrict__ xT) {
    __shared__ float tile[64][65];
    int b = blockIdx.z, n0 = blockIdx.y * 64, c0 = blockIdx.x * 64;
    int t = threadIdx.x;
    const float* xb = x + (size_t)b * CIN * NN;
#pragma unroll
    for (int i = 0; i < 4; i++) {
        int c = (t >> 4) + i * 16;
        int n = (t & 15) * 4;
        float4 v = *(const float4*)&xb[(size_t)(c0 + c) * NN + n0 + n];
        tile[c][n + 0] = v.x; tile[c][n + 1] = v.y;
        tile[c][n + 2] = v.z; tile[c][n + 3] = v.w;
    }
    __syncthreads();
    F16* xTb = xT + (size_t)b * NN * CIN;
#pragma unroll
    for (int i = 0; i < 4; i++) {
        int n = (t >> 4) + i * 16;
        int c = (t & 15) * 4;
        f16x4 o;
        o[0] = (F16)tile[c + 0][n]; o[1] = (F16)tile[c + 1][n];
        o[2] = (F16)tile[c + 2][n]; o[3] = (F16)tile[c + 3][n];
        *(f16x4*)&xTb[(size_t)(n0 + n) * CIN + c0 + c] = o;
    }
}

// ---------------------------------------------------------------- K/V GEMM
__global__ __launch_bounds__(256) void k_kv_gemm(
    const F16* __restrict__ xT,
    const float* __restrict__ key_w, const float* __restrict__ key_b,
    const float* __restrict__ gamma, const float* __restrict__ beta,
    const float* __restrict__ mean,  const float* __restrict__ var,
    const float* __restrict__ value_w, const float* __restrict__ value_b,
    F16* __restrict__ KQt, F16* __restrict__ Vg) {
    __shared__ F16 Al[128][40];
    __shared__ F16 Bl[128][40];
    int b = blockIdx.z;
    int m0 = blockIdx.y * 128;
    int n0 = blockIdx.x * 128;
    int t = threadIdx.x, w = t >> 6, l = t & 63;
    int wr = w >> 1, wc = w & 1;
    int lr = l >> 4, lc = l & 15;
    f32x4 acc[4][4];
    const f32x4 fz = {0.f, 0.f, 0.f, 0.f};
#pragma unroll
    for (int i = 0; i < 4; i++)
#pragma unroll
        for (int j = 0; j < 4; j++) acc[i][j] = fz;
    const F16* xb = xT + (size_t)b * NN * CIN;

    for (int kt = 0; kt < CIN / 32; kt++) {
        int c0 = kt * 32;
        __syncthreads();
#pragma unroll
        for (int p = 0; p < 4; p++) {
            int row = (t >> 3) + p * 32;
            int cc = (t & 7) * 4;
            int rg = m0 + row;
            const float* src = (rg < 256) ? (key_w + (size_t)rg * CIN)
                                          : (value_w + (size_t)(rg - 256) * CIN);
            float4 v = *(const float4*)&src[c0 + cc];
            f16x4 h; h[0] = (F16)v.x; h[1] = (F16)v.y; h[2] = (F16)v.z; h[3] = (F16)v.w;
            *(f16x4*)&Al[row][cc] = h;
        }
#pragma unroll
        for (int p = 0; p < 2; p++) {
            int row = (t >> 2) + p * 64;
            int cc = (t & 3) * 8;
            *(int4*)&Bl[row][cc] = *(const int4*)&xb[(size_t)(n0 + row) * CIN + c0 + cc];
        }
        __syncthreads();
        f16x8 a[4];
#pragma unroll
        for (int fi = 0; fi < 4; fi++)
            a[fi] = *(f16x8*)&Al[wr * 64 + fi * 16 + lc][lr * 8];
#pragma unroll
        for (int fj = 0; fj < 4; fj++) {
            f16x8 bb = *(f16x8*)&Bl[wc * 64 + fj * 16 + lc][lr * 8];
#pragma unroll
            for (int fi = 0; fi < 4; fi++)
                acc[fi][fj] = __builtin_amdgcn_mfma_f32_16x16x32_f16(a[fi], bb, acc[fi][fj], 0, 0, 0);
        }
    }

    if (m0 < 256) {
#pragma unroll
        for (int fi = 0; fi < 4; fi++) {
            int ch0 = m0 + wr * 64 + fi * 16 + lr * 4;
            float invs[4], mns[4], bts[4], kbs[4];
#pragma unroll
            for (int r = 0; r < 4; r++) {
                int ch = ch0 + r;
                invs[r] = gamma[ch] * rsqrtf(var[ch] + BNEPS);
                mns[r] = mean[ch]; bts[r] = beta[ch]; kbs[r] = key_b[ch];
            }
#pragma unroll
            for (int fj = 0; fj < 4; fj++) {
                int n = n0 + wc * 64 + fj * 16 + lc;
                f16x4 o;
#pragma unroll
                for (int r = 0; r < 4; r++) {
                    float v = (acc[fi][fj][r] + kbs[r] - mns[r]) * invs[r] + bts[r];
                    v = fmaxf(v, 0.0f);
                    o[r] = (F16)v;
                }
                *(f16x4*)&KQt[((size_t)b * NN + n) * KCH + ch0] = o;
            }
        }
    } else {
#pragma unroll
        for (int fi = 0; fi < 4; fi++) {
            int v0 = m0 - 256 + wr * 64 + fi * 16 + lr * 4;
#pragma unroll
            for (int fj = 0; fj < 4; fj++) {
                int n = n0 + wc * 64 + fj * 16 + lc;
#pragma unroll
                for (int r = 0; r < 4; r++) {
                    float vv = acc[fi][fj][r] + value_b[v0 + r];
                    Vg[((size_t)b * KCH + v0 + r) * NN + n] = (F16)vv;
                }
            }
        }
    }
}

// ---------------------------------------------------------------- flash attention
// 2 blocks/CU (LDS 78 KB): Q in registers; reg-staged async K/V prefetch;
// defer-max online softmax (THR=8).
__global__ __launch_bounds__(256, 2) void k_flash(const F16* __restrict__ KQt,
                                                  const F16* __restrict__ Vg,
                                                  F16* __restrict__ ctxT) {
    __shared__ F16 Kl[64 * 264];
    __shared__ F16 Vl[256 * 72];
    __shared__ F16 Pl[4][16 * 72];
    int q = blockIdx.x;
    int xcd = q & 7;
    int b = xcd >> 1;                       // batch pinned to an XCD pair (L2 locality)
    int nt = (xcd & 1) * 32 + (q >> 3);
    int n0 = nt * 64;
    int t = threadIdx.x, w = t >> 6, l = t & 63;
    int lr = l >> 4, lc = l & 15;
    const F16* kqb = KQt + (size_t)b * NN * KCH;
    const F16* vgb = Vg + (size_t)b * KCH * NN;

    // Q tile -> registers (A-fragment layout: row = lc, cols = ks*32 + lr*8)
    f16x8 qreg[8];
    {
        const F16* qrow = kqb + (size_t)(n0 + w * 16 + lc) * KCH + lr * 8;
#pragma unroll
        for (int ks = 0; ks < 8; ks++)
            qreg[ks] = *(const f16x8*)&qrow[ks * 32];
    }

    // stage registers for async prefetch
    int4 kst[8], vst[8];
    int krow = t >> 5, kcol = (t & 31) * 8;       // K: 8 rows apart
    int vrow = t >> 3, vcol = (t & 7) * 8;        // V: 32 rows apart
#define PREF(m0_)                                                              \
    {                                                                          \
        _Pragma("unroll") for (int p = 0; p < 8; p++)                          \
            kst[p] = *(const int4*)&kqb[(size_t)((m0_) + krow + p * 8) * KCH + kcol]; \
        _Pragma("unroll") for (int p = 0; p < 8; p++)                          \
            vst[p] = *(const int4*)&vgb[(size_t)(vrow + p * 32) * NN + (m0_) + vcol]; \
    }

    f32x4 acc[16];
    const f32x4 fz = {0.f, 0.f, 0.f, 0.f};
#pragma unroll
    for (int i = 0; i < 16; i++) acc[i] = fz;
    float m_run[4] = {-1e30f, -1e30f, -1e30f, -1e30f};
    float l_run[4] = {0.f, 0.f, 0.f, 0.f};
    const float scale = 0.0625f;

    PREF(0);

    for (int mt = 0; mt < 64; mt++) {
        __syncthreads();                      // previous compute done with Kl/Vl
        // write staged tile to LDS
#pragma unroll
        for (int p = 0; p < 8; p++)
            *(int4*)&Kl[(krow + p * 8) * 264 + kcol] = kst[p];
#pragma unroll
        for (int p = 0; p < 8; p++)
            *(int4*)&Vl[(vrow + p * 32) * 72 + vcol] = vst[p];
        if (mt < 63) PREF((mt + 1) * 64);     // loads fly during compute below
        __syncthreads();                      // tile visible

        // S = Q K^T  (per wave: 16 q-rows x 64 k-cols, contraction 256)
        f32x4 s[4];
#pragma unroll
        for (int f = 0; f < 4; f++) s[f] = fz;
#pragma unroll
        for (int ks = 0; ks < 8; ks++) {
#pragma unroll
            for (int f = 0; f < 4; f++) {
                f16x8 bb = *(f16x8*)&Kl[(f * 16 + lc) * 264 + ks * 32 + lr * 8];
                s[f] = __builtin_amdgcn_mfma_f32_16x16x32_f16(qreg[ks], bb, s[f], 0, 0, 0);
            }
        }

        // online softmax with deferred rescale (rows live across the 16-lane group)
#pragma unroll
        for (int r = 0; r < 4; r++) {
            float mx = fmaxf(fmaxf(s[0][r], s[1][r]), fmaxf(s[2][r], s[3][r]));
#pragma unroll
            for (int off = 1; off < 16; off <<= 1) mx = fmaxf(mx, __shfl_xor(mx, off, 64));
            mx *= scale;
            if (mx > m_run[r] + 8.0f) {       // uniform across the 16-lane group
                float corr = __expf(m_run[r] - mx);
                m_run[r] = mx;
                l_run[r] *= corr;
#pragma unroll
                for (int fv = 0; fv < 16; fv++) acc[fv][r] *= corr;
            }
            float ps = 0.0f;
#pragma unroll
            for (int f = 0; f < 4; f++) {
                float p = __expf(s[f][r] * scale - m_run[r]);
                ps += p;
                Pl[w][(lr * 4 + r) * 72 + f * 16 + lc] = (F16)p;
            }
#pragma unroll
            for (int off = 1; off < 16; off <<= 1) ps += __shfl_xor(ps, off, 64);
            l_run[r] += ps;
        }
        // Pl is per-wave and DS ops are in-order within a wave: no barrier needed

        // ctx += P V^T   (per wave: 16 q-rows x 256 v, contraction 64)
#pragma unroll
        for (int ks = 0; ks < 2; ks++) {
            f16x8 a = *(f16x8*)&Pl[w][lc * 72 + ks * 32 + lr * 8];
#pragma unroll
            for (int fv = 0; fv < 16; fv++) {
                f16x8 bb = *(f16x8*)&Vl[(fv * 16 + lc) * 72 + ks * 32 + lr * 8];
                acc[fv] = __builtin_amdgcn_mfma_f32_16x16x32_f16(a, bb, acc[fv], 0, 0, 0);
            }
        }
    }

    // epilogue: ctxT[n][v] = acc / l_run
    F16* cb = ctxT + (size_t)b * NN * KCH;
#pragma unroll
    for (int r = 0; r < 4; r++) {
        int n = n0 + w * 16 + lr * 4 + r;
        float inv = 1.0f / l_run[r];
#pragma unroll
        for (int fv = 0; fv < 16; fv++)
            cb[(size_t)n * KCH + fv * 16 + lc] = (F16)(acc[fv][r] * inv);
    }
#undef PREF
}

// ---------------------------------------------------------------- out GEMM
__global__ __launch_bounds__(256) void k_out_gemm(const F16* __restrict__ ctxT,
                                                  const float* __restrict__ w_w,
                                                  const float* __restrict__ w_b,
                                                  float* __restrict__ out) {
    __shared__ F16 Al[128][40];
    __shared__ F16 Bl[128][40];
    int b = blockIdx.z;
    int m0 = blockIdx.y * 128;
    int n0 = blockIdx.x * 128;
    int t = threadIdx.x, w = t >> 6, l = t & 63;
    int wr = w >> 1, wc = w & 1;
    int lr = l >> 4, lc = l & 15;
    f32x4 acc[4][4];
    const f32x4 fz = {0.f, 0.f, 0.f, 0.f};
#pragma unroll
    for (int i = 0; i < 4; i++)
#pragma unroll
        for (int j = 0; j < 4; j++) acc[i][j] = fz;
    const F16* cb = ctxT + (size_t)b * NN * KCH;

    for (int kt = 0; kt < KCH / 32; kt++) {
        int c0 = kt * 32;
        __syncthreads();
#pragma unroll
        for (int p = 0; p < 4; p++) {
            int row = (t >> 3) + p * 32;
            int cc = (t & 7) * 4;
            float4 v = *(const float4*)&w_w[(size_t)(m0 + row) * KCH + c0 + cc];
            f16x4 h; h[0] = (F16)v.x; h[1] = (F16)v.y; h[2] = (F16)v.z; h[3] = (F16)v.w;
            *(f16x4*)&Al[row][cc] = h;
        }
#pragma unroll
        for (int p = 0; p < 2; p++) {
            int row = (t >> 2) + p * 64;
            int cc = (t & 3) * 8;
            *(int4*)&Bl[row][cc] = *(const int4*)&cb[(size_t)(n0 + row) * KCH + c0 + cc];
        }
        __syncthreads();
        f16x8 a[4];
#pragma unroll
        for (int fi = 0; fi < 4; fi++)
            a[fi] = *(f16x8*)&Al[wr * 64 + fi * 16 + lc][lr * 8];
#pragma unroll
        for (int fj = 0; fj < 4; fj++) {
            f16x8 bb = *(f16x8*)&Bl[wc * 64 + fj * 16 + lc][lr * 8];
#pragma unroll
            for (int fi = 0; fi < 4; fi++)
                acc[fi][fj] = __builtin_amdgcn_mfma_f32_16x16x32_f16(a[fi], bb, acc[fi][fj], 0, 0, 0);
        }
    }

#pragma unroll
    for (int fi = 0; fi < 4; fi++) {
        int o0 = m0 + wr * 64 + fi * 16 + lr * 4;
#pragma unroll
        for (int fj = 0; fj < 4; fj++) {
            int n = n0 + wc * 64 + fj * 16 + lc;
#pragma unroll
            for (int r = 0; r < 4; r++) {
                out[((size_t)b * OCH + o0 + r) * NN + n] = acc[fi][fj][r] + w_b[o0 + r];
            }
        }
    }
}

// ---------------------------------------------------------------- launch
extern "C" void kernel_launch(void* const* d_in, const int* in_sizes, int n_in,
                              void* d_out, int out_size, void* d_ws, size_t ws_size,
                              hipStream_t stream) {
    const float* x       = (const float*)d_in[0];
    const float* key_w   = (const float*)d_in[1];
    const float* key_b   = (const float*)d_in[2];
    const float* gamma   = (const float*)d_in[3];
    const float* beta    = (const float*)d_in[4];
    const float* mean    = (const float*)d_in[5];
    const float* var     = (const float*)d_in[6];
    const float* value_w = (const float*)d_in[7];
    const float* value_b = (const float*)d_in[8];
    const float* w_w     = (const float*)d_in[9];
    const float* w_b     = (const float*)d_in[10];
    float* out = (float*)d_out;
    char* ws = (char*)d_ws;
    F16* xT   = (F16*)(ws + XT_OFF);
    F16* KQt  = (F16*)(ws + KQT_OFF);
    F16* Vg   = (F16*)(ws + VG_OFF);
    F16* ctxT = (F16*)(ws + CTX_OFF);

    hipLaunchKernelGGL(k_transpose, dim3(8, 64, 4), dim3(256), 0, stream, x, xT);
    hipLaunchKernelGGL(k_kv_gemm, dim3(32, 4, 4), dim3(256), 0, stream,
                       xT, key_w, key_b, gamma, beta, mean, var, value_w, value_b, KQt, Vg);
    hipLaunchKernelGGL(k_flash, dim3(256), dim3(256), 0, stream, KQt, Vg, ctxT);
    hipLaunchKernelGGL(k_out_gemm, dim3(32, 4, 4), dim3(256), 0, stream, ctxT, w_w, w_b, out);
}

// Round 3
// 199.670 us; speedup vs baseline: 2.2241x; 2.2241x over previous
//
#include <hip/hip_runtime.h>

#define F16 _Float16
typedef _Float16 f16x8 __attribute__((ext_vector_type(8)));
typedef _Float16 f16x4 __attribute__((ext_vector_type(4)));
typedef float f32x4 __attribute__((ext_vector_type(4)));

#define NB    4
#define CIN   512
#define NN    4096
#define KCH   256
#define OCH   512
#define BNEPS 1e-5f
#define KSETS 2
#define KPERSET (NN / KSETS)

// workspace layout (bytes) — proven ws >= 42M in rounds 1-2.
// xT [0,16.78M) is dead after k_kv_gemm -> reused for the split-K partials.
// KQt region is dead after k_flash -> reused for ctxT.
#define XT_OFF    0u                        // [B][N][C] f16, 16.78 MB (then parts)
#define PARTS_OFF 0u                        // [S][B][N][V] f16, 2 x 8.39 MB
#define KQT_OFF   16777216u                 // [B][N][K] f16, 8.39 MB
#define CTX_OFF   16777216u                 // [B][N][V] f16 (after flash)
#define VG_OFF    25165824u                 // [B][V][N] f16, 8.39 MB
#define L_OFF     33554432u                 // [S][B][N] f32, 131 KB
#define PSET      ((size_t)NB * NN * KCH)   // elements per partial set

// ---------------------------------------------------------------- transpose
__global__ __launch_bounds__(256) void k_transpose(const float* __restrict__ x,
                                                   F16* __restrict__ xT) {
    __shared__ float tile[64][65];
    int b = blockIdx.z, n0 = blockIdx.y * 64, c0 = blockIdx.x * 64;
    int t = threadIdx.x;
    const float* xb = x + (size_t)b * CIN * NN;
#pragma unroll
    for (int i = 0; i < 4; i++) {
        int c = (t >> 4) + i * 16;
        int n = (t & 15) * 4;
        float4 v = *(const float4*)&xb[(size_t)(c0 + c) * NN + n0 + n];
        tile[c][n + 0] = v.x; tile[c][n + 1] = v.y;
        tile[c][n + 2] = v.z; tile[c][n + 3] = v.w;
    }
    __syncthreads();
    F16* xTb = xT + (size_t)b * NN * CIN;
#pragma unroll
    for (int i = 0; i < 4; i++) {
        int n = (t >> 4) + i * 16;
        int c = (t & 15) * 4;
        f16x4 o;
        o[0] = (F16)tile[c + 0][n]; o[1] = (F16)tile[c + 1][n];
        o[2] = (F16)tile[c + 2][n]; o[3] = (F16)tile[c + 3][n];
        *(f16x4*)&xTb[(size_t)(n0 + n) * CIN + c0 + c] = o;
    }
}

// ---------------------------------------------------------------- K/V GEMM
__global__ __launch_bounds__(256) void k_kv_gemm(
    const F16* __restrict__ xT,
    const float* __restrict__ key_w, const float* __restrict__ key_b,
    const float* __restrict__ gamma, const float* __restrict__ beta,
    const float* __restrict__ mean,  const float* __restrict__ var,
    const float* __restrict__ value_w, const float* __restrict__ value_b,
    F16* __restrict__ KQt, F16* __restrict__ Vg) {
    __shared__ F16 Al[128][40];
    __shared__ F16 Bl[128][40];
    int b = blockIdx.z;
    int m0 = blockIdx.y * 128;
    int n0 = blockIdx.x * 128;
    int t = threadIdx.x, w = t >> 6, l = t & 63;
    int wr = w >> 1, wc = w & 1;
    int lr = l >> 4, lc = l & 15;
    f32x4 acc[4][4];
    const f32x4 fz = {0.f, 0.f, 0.f, 0.f};
#pragma unroll
    for (int i = 0; i < 4; i++)
#pragma unroll
        for (int j = 0; j < 4; j++) acc[i][j] = fz;
    const F16* xb = xT + (size_t)b * NN * CIN;

    for (int kt = 0; kt < CIN / 32; kt++) {
        int c0 = kt * 32;
        __syncthreads();
#pragma unroll
        for (int p = 0; p < 4; p++) {
            int row = (t >> 3) + p * 32;
            int cc = (t & 7) * 4;
            int rg = m0 + row;
            const float* src = (rg < 256) ? (key_w + (size_t)rg * CIN)
                                          : (value_w + (size_t)(rg - 256) * CIN);
            float4 v = *(const float4*)&src[c0 + cc];
            f16x4 h; h[0] = (F16)v.x; h[1] = (F16)v.y; h[2] = (F16)v.z; h[3] = (F16)v.w;
            *(f16x4*)&Al[row][cc] = h;
        }
#pragma unroll
        for (int p = 0; p < 2; p++) {
            int row = (t >> 2) + p * 64;
            int cc = (t & 3) * 8;
            *(int4*)&Bl[row][cc] = *(const int4*)&xb[(size_t)(n0 + row) * CIN + c0 + cc];
        }
        __syncthreads();
        f16x8 a[4];
#pragma unroll
        for (int fi = 0; fi < 4; fi++)
            a[fi] = *(f16x8*)&Al[wr * 64 + fi * 16 + lc][lr * 8];
#pragma unroll
        for (int fj = 0; fj < 4; fj++) {
            f16x8 bb = *(f16x8*)&Bl[wc * 64 + fj * 16 + lc][lr * 8];
#pragma unroll
            for (int fi = 0; fi < 4; fi++)
                acc[fi][fj] = __builtin_amdgcn_mfma_f32_16x16x32_f16(a[fi], bb, acc[fi][fj], 0, 0, 0);
        }
    }

    if (m0 < 256) {
#pragma unroll
        for (int fi = 0; fi < 4; fi++) {
            int ch0 = m0 + wr * 64 + fi * 16 + lr * 4;
            float invs[4], mns[4], bts[4], kbs[4];
#pragma unroll
            for (int r = 0; r < 4; r++) {
                int ch = ch0 + r;
                invs[r] = gamma[ch] * rsqrtf(var[ch] + BNEPS);
                mns[r] = mean[ch]; bts[r] = beta[ch]; kbs[r] = key_b[ch];
            }
#pragma unroll
            for (int fj = 0; fj < 4; fj++) {
                int n = n0 + wc * 64 + fj * 16 + lc;
                f16x4 o;
#pragma unroll
                for (int r = 0; r < 4; r++) {
                    float v = (acc[fi][fj][r] + kbs[r] - mns[r]) * invs[r] + bts[r];
                    v = fmaxf(v, 0.0f);
                    o[r] = (F16)v;
                }
                *(f16x4*)&KQt[((size_t)b * NN + n) * KCH + ch0] = o;
            }
        }
    } else {
#pragma unroll
        for (int fi = 0; fi < 4; fi++) {
            int v0 = m0 - 256 + wr * 64 + fi * 16 + lr * 4;
#pragma unroll
            for (int fj = 0; fj < 4; fj++) {
                int n = n0 + wc * 64 + fj * 16 + lc;
#pragma unroll
                for (int r = 0; r < 4; r++) {
                    float vv = acc[fi][fj][r] + value_b[v0 + r];
                    Vg[((size_t)b * KCH + v0 + r) * NN + n] = (F16)vv;
                }
            }
        }
    }
}

// ---------------------------------------------------------------- flash attention (split-K S=2)
// 512 blocks = 2/CU (LDS 79.4 KB). Q in registers. Each block covers 64 q-rows
// x 2048 keys; writes normalized partial ctx + L = m + ln(l).
__global__ __launch_bounds__(256, 2) void k_flash(const F16* __restrict__ KQt,
                                                  const F16* __restrict__ Vg,
                                                  F16* __restrict__ parts,
                                                  float* __restrict__ Lbuf) {
    __shared__ F16 Kl[64 * 264];
    __shared__ F16 Vl[256 * 72];
    __shared__ F16 Pl[4][16 * 68];
    int bid = blockIdx.x;
    int xcd = bid & 7;
    int b = xcd >> 1;                          // batch pinned to an XCD pair
    int hi = bid >> 3;
    int kset = hi & 1;
    int qtile = (xcd & 1) * 32 + (hi >> 1);    // 0..63
    int n0 = qtile * 64;
    int kbase = kset * KPERSET;
    int t = threadIdx.x, w = t >> 6, l = t & 63;
    int lr = l >> 4, lc = l & 15;
    const F16* kqb = KQt + (size_t)b * NN * KCH;
    const F16* vgb = Vg + (size_t)b * KCH * NN;

    // Q tile -> registers (A-fragment: row = w*16+lc, cols = ks*32 + lr*8)
    f16x8 qreg[8];
    {
        const F16* qrow = kqb + (size_t)(n0 + w * 16 + lc) * KCH + lr * 8;
#pragma unroll
        for (int ks = 0; ks < 8; ks++)
            qreg[ks] = *(const f16x8*)&qrow[ks * 32];
    }

    f32x4 acc[16];
    const f32x4 fz = {0.f, 0.f, 0.f, 0.f};
#pragma unroll
    for (int i = 0; i < 16; i++) acc[i] = fz;
    float m_run[4] = {-1e30f, -1e30f, -1e30f, -1e30f};
    float l_run[4] = {0.f, 0.f, 0.f, 0.f};
    const float scale = 0.0625f;

    int krow = t >> 5, kcol = (t & 31) * 8;    // K staging: 8 rows/pass
    int vrow = t >> 3, vcol = (t & 7) * 8;     // V staging: 32 rows/pass

    for (int mt = 0; mt < KPERSET / 64; mt++) {
        int m0 = kbase + mt * 64;
        __syncthreads();
        // stage K tile [64][256] -> padded [64][264] (load->write, no arrays)
#pragma unroll
        for (int p = 0; p < 8; p++) {
            int4 tmp = *(const int4*)&kqb[(size_t)(m0 + krow + p * 8) * KCH + kcol];
            *(int4*)&Kl[(krow + p * 8) * 264 + kcol] = tmp;
        }
        // stage V tile [256 v][64 m] -> padded [256][72]
#pragma unroll
        for (int p = 0; p < 8; p++) {
            int4 tmp = *(const int4*)&vgb[(size_t)(vrow + p * 32) * NN + m0 + vcol];
            *(int4*)&Vl[(vrow + p * 32) * 72 + vcol] = tmp;
        }
        __syncthreads();

        // S = Q K^T  (per wave: 16 q-rows x 64 k-cols, contraction 256)
        f32x4 s[4];
#pragma unroll
        for (int f = 0; f < 4; f++) s[f] = fz;
#pragma unroll
        for (int ks = 0; ks < 8; ks++) {
#pragma unroll
            for (int f = 0; f < 4; f++) {
                f16x8 bb = *(f16x8*)&Kl[(f * 16 + lc) * 264 + ks * 32 + lr * 8];
                s[f] = __builtin_amdgcn_mfma_f32_16x16x32_f16(qreg[ks], bb, s[f], 0, 0, 0);
            }
        }

        // online softmax, deferred rescale (THR=8); rows uniform across 16-lane group
#pragma unroll
        for (int r = 0; r < 4; r++) {
            float mx = fmaxf(fmaxf(s[0][r], s[1][r]), fmaxf(s[2][r], s[3][r]));
#pragma unroll
            for (int off = 1; off < 16; off <<= 1) mx = fmaxf(mx, __shfl_xor(mx, off, 64));
            mx *= scale;
            if (mx > m_run[r] + 8.0f) {
                float corr = __expf(m_run[r] - mx);
                m_run[r] = mx;
                l_run[r] *= corr;
#pragma unroll
                for (int fv = 0; fv < 16; fv++) acc[fv][r] *= corr;
            }
            float ps = 0.0f;
#pragma unroll
            for (int f = 0; f < 4; f++) {
                float p = __expf(s[f][r] * scale - m_run[r]);
                ps += p;
                Pl[w][(lr * 4 + r) * 68 + f * 16 + lc] = (F16)p;
            }
#pragma unroll
            for (int off = 1; off < 16; off <<= 1) ps += __shfl_xor(ps, off, 64);
            l_run[r] += ps;
        }
        // Pl is per-wave; DS ops in-order within a wave -> no barrier

        // ctx += P V^T   (per wave: 16 q-rows x 256 v, contraction 64)
#pragma unroll
        for (int ks = 0; ks < 2; ks++) {
            f16x8 a = *(f16x8*)&Pl[w][lc * 68 + ks * 32 + lr * 8];
#pragma unroll
            for (int fv = 0; fv < 16; fv++) {
                f16x8 bb = *(f16x8*)&Vl[(fv * 16 + lc) * 72 + ks * 32 + lr * 8];
                acc[fv] = __builtin_amdgcn_mfma_f32_16x16x32_f16(a, bb, acc[fv], 0, 0, 0);
            }
        }
    }

    // epilogue: normalized partial + L = m + ln(l)
    F16* cb = parts + (size_t)kset * PSET + (size_t)b * NN * KCH;
    float* Lb = Lbuf + (size_t)kset * NB * NN + (size_t)b * NN;
#pragma unroll
    for (int r = 0; r < 4; r++) {
        int n = n0 + w * 16 + lr * 4 + r;
        float inv = 1.0f / l_run[r];
#pragma unroll
        for (int fv = 0; fv < 16; fv++)
            cb[(size_t)n * KCH + fv * 16 + lc] = (F16)(acc[fv][r] * inv);
        if (lc == 0) Lb[n] = m_run[r] + __logf(l_run[r]);
    }
}

// ---------------------------------------------------------------- combine (split-K merge)
__global__ __launch_bounds__(256) void k_combine(const F16* __restrict__ parts,
                                                 const float* __restrict__ Lbuf,
                                                 F16* __restrict__ ctxT) {
    int idx = blockIdx.x * 256 + threadIdx.x;       // over B*N*32
    int n = idx >> 5;                               // 0..B*N-1
    int v8 = (idx & 31) * 8;
    float L0 = Lbuf[n], L1 = Lbuf[NB * NN + n];
    float M = fmaxf(L0, L1);
    float w0 = __expf(L0 - M), w1 = __expf(L1 - M);
    float inv = 1.0f / (w0 + w1);
    w0 *= inv; w1 *= inv;
    f16x8 p0 = *(const f16x8*)&parts[(size_t)n * KCH + v8];
    f16x8 p1 = *(const f16x8*)&parts[PSET + (size_t)n * KCH + v8];
    f16x8 o;
#pragma unroll
    for (int j = 0; j < 8; j++)
        o[j] = (F16)(w0 * (float)p0[j] + w1 * (float)p1[j]);
    *(f16x8*)&ctxT[(size_t)n * KCH + v8] = o;
}

// ---------------------------------------------------------------- out GEMM
__global__ __launch_bounds__(256) void k_out_gemm(const F16* __restrict__ ctxT,
                                                  const float* __restrict__ w_w,
                                                  const float* __restrict__ w_b,
                                                  float* __restrict__ out) {
    __shared__ F16 Al[128][40];
    __shared__ F16 Bl[128][40];
    int b = blockIdx.z;
    int m0 = blockIdx.y * 128;
    int n0 = blockIdx.x * 128;
    int t = threadIdx.x, w = t >> 6, l = t & 63;
    int wr = w >> 1, wc = w & 1;
    int lr = l >> 4, lc = l & 15;
    f32x4 acc[4][4];
    const f32x4 fz = {0.f, 0.f, 0.f, 0.f};
#pragma unroll
    for (int i = 0; i < 4; i++)
#pragma unroll
        for (int j = 0; j < 4; j++) acc[i][j] = fz;
    const F16* cb = ctxT + (size_t)b * NN * KCH;

    for (int kt = 0; kt < KCH / 32; kt++) {
        int c0 = kt * 32;
        __syncthreads();
#pragma unroll
        for (int p = 0; p < 4; p++) {
            int row = (t >> 3) + p * 32;
            int cc = (t & 7) * 4;
            float4 v = *(const float4*)&w_w[(size_t)(m0 + row) * KCH + c0 + cc];
            f16x4 h; h[0] = (F16)v.x; h[1] = (F16)v.y; h[2] = (F16)v.z; h[3] = (F16)v.w;
            *(f16x4*)&Al[row][cc] = h;
        }
#pragma unroll
        for (int p = 0; p < 2; p++) {
            int row = (t >> 2) + p * 64;
            int cc = (t & 3) * 8;
            *(int4*)&Bl[row][cc] = *(const int4*)&cb[(size_t)(n0 + row) * KCH + c0 + cc];
        }
        __syncthreads();
        f16x8 a[4];
#pragma unroll
        for (int fi = 0; fi < 4; fi++)
            a[fi] = *(f16x8*)&Al[wr * 64 + fi * 16 + lc][lr * 8];
#pragma unroll
        for (int fj = 0; fj < 4; fj++) {
            f16x8 bb = *(f16x8*)&Bl[wc * 64 + fj * 16 + lc][lr * 8];
#pragma unroll
            for (int fi = 0; fi < 4; fi++)
                acc[fi][fj] = __builtin_amdgcn_mfma_f32_16x16x32_f16(a[fi], bb, acc[fi][fj], 0, 0, 0);
        }
    }

#pragma unroll
    for (int fi = 0; fi < 4; fi++) {
        int o0 = m0 + wr * 64 + fi * 16 + lr * 4;
#pragma unroll
        for (int fj = 0; fj < 4; fj++) {
            int n = n0 + wc * 64 + fj * 16 + lc;
#pragma unroll
            for (int r = 0; r < 4; r++) {
                out[((size_t)b * OCH + o0 + r) * NN + n] = acc[fi][fj][r] + w_b[o0 + r];
            }
        }
    }
}

// ---------------------------------------------------------------- launch
extern "C" void kernel_launch(void* const* d_in, const int* in_sizes, int n_in,
                              void* d_out, int out_size, void* d_ws, size_t ws_size,
                              hipStream_t stream) {
    const float* x       = (const float*)d_in[0];
    const float* key_w   = (const float*)d_in[1];
    const float* key_b   = (const float*)d_in[2];
    const float* gamma   = (const float*)d_in[3];
    const float* beta    = (const float*)d_in[4];
    const float* mean    = (const float*)d_in[5];
    const float* var     = (const float*)d_in[6];
    const float* value_w = (const float*)d_in[7];
    const float* value_b = (const float*)d_in[8];
    const float* w_w     = (const float*)d_in[9];
    const float* w_b     = (const float*)d_in[10];
    float* out = (float*)d_out;
    char* ws = (char*)d_ws;
    F16*   xT    = (F16*)(ws + XT_OFF);
    F16*   parts = (F16*)(ws + PARTS_OFF);   // overlays xT (dead after kv_gemm)
    F16*   KQt   = (F16*)(ws + KQT_OFF);
    F16*   ctxT  = (F16*)(ws + CTX_OFF);     // overlays KQt (dead after flash)
    F16*   Vg    = (F16*)(ws + VG_OFF);
    float* Lbuf  = (float*)(ws + L_OFF);

    hipLaunchKernelGGL(k_transpose, dim3(8, 64, 4), dim3(256), 0, stream, x, xT);
    hipLaunchKernelGGL(k_kv_gemm, dim3(32, 4, 4), dim3(256), 0, stream,
                       xT, key_w, key_b, gamma, beta, mean, var, value_w, value_b, KQt, Vg);
    hipLaunchKernelGGL(k_flash, dim3(512), dim3(256), 0, stream, KQt, Vg, parts, Lbuf);
    hipLaunchKernelGGL(k_combine, dim3(2048), dim3(256), 0, stream, parts, Lbuf, ctxT);
    hipLaunchKernelGGL(k_out_gemm, dim3(32, 4, 4), dim3(256), 0, stream, ctxT, w_w, w_b, out);
}